// Round 14
// baseline (234.079 us; speedup 1.0000x reference)
//
#include <hip/hip_runtime.h>
#include <hip/hip_fp16.h>

// GCN: 100K nodes, 2.5M edges, dims 4 -> 32 -> (32x32 conv x3) -> 3.
// Round 14: (a) SINGLE-LOOP gather over the quad-sorted CSR. R13's per-segment
// loop was redundant: segments are contiguous and already quad-ordered, so one
// linear walk gives the identical (soft-phased) traversal -- but with ONE
// pipeline fill + ONE tail per node instead of four (avg segment 6.25 edges
// meant ~30% of edges ran serially in R13). Sortdeg keeps the 1024-key sort,
// emits rowptr[N+1] + dinv. (b) k_binscan folded into k_sortdeg (each block
// reduces bintot[0..b) itself) -- one fewer dispatch. Rest = R12/R13.

constexpr int N_NODES = 100000;
constexpr int N_EDGES = 2500000;
constexpr int QDIV    = 25000;                             // src quad divisor
constexpr int BUCKET  = 256;
constexpr int NBUCK   = (N_NODES + BUCKET - 1) / BUCKET;   // 391
constexpr int NBLK    = 1024;                              // build blocks
constexpr int CHUNK   = (N_EDGES + NBLK - 1) / NBLK;       // 2442
constexpr int SCAP    = 8192;                              // sortdeg LDS stage cap
constexpr int PERLANE = NBLK / 64;                         // 16

// ---- build K1: per-block LDS counting sort by bucket; contiguous write ----
__global__ __launch_bounds__(256) void k_binfill(const int* __restrict__ ei,
                                                 int* __restrict__ binned,
                                                 int* __restrict__ blkbin,
                                                 int* __restrict__ locoff) {
    __shared__ int cnt[NBUCK];
    __shared__ int cur[NBUCK];
    __shared__ int sc[512];
    __shared__ int stage[CHUNK];
    int tid = threadIdx.x;
    int blk = blockIdx.x;
    int beg = blk * CHUNK;
    int end = min(beg + CHUNK, N_EDGES);
    int m = end - beg;

    for (int i = tid; i < NBUCK; i += 256) cnt[i] = 0;
    __syncthreads();
    for (int e = beg + tid; e < end; e += 256)
        atomicAdd(&cnt[ei[N_EDGES + e] >> 8], 1);
    __syncthreads();

    sc[tid]       = (tid < NBUCK) ? cnt[tid] : 0;
    sc[tid + 256] = (tid + 256 < NBUCK) ? cnt[tid + 256] : 0;
    __syncthreads();
#pragma unroll
    for (int o = 1; o < 512; o <<= 1) {
        int a0 = (tid >= o) ? sc[tid - o] : 0;
        int a1 = (tid + 256 >= o) ? sc[tid + 256 - o] : 0;
        __syncthreads();
        sc[tid] += a0; sc[tid + 256] += a1;
        __syncthreads();
    }
    if (tid < NBUCK) {
        int excl = sc[tid] - cnt[tid];
        cur[tid] = excl;
        blkbin[tid * NBLK + blk] = cnt[tid];
        locoff[blk * NBUCK + tid] = beg + excl;
    }
    if (tid + 256 < NBUCK) {
        int i = tid + 256;
        int excl = sc[i] - cnt[i];
        cur[i] = excl;
        blkbin[i * NBLK + blk] = cnt[i];
        locoff[blk * NBUCK + i] = beg + excl;
    }
    __syncthreads();

    for (int e = beg + tid; e < end; e += 256) {
        int s = ei[e];
        int d = ei[N_EDGES + e];
        int pos = atomicAdd(&cur[d >> 8], 1);
        stage[pos] = (s << 8) | (d & 255);     // src<17b><<8 | dst_local<8b>
    }
    __syncthreads();
    for (int i = tid; i < m; i += 256) binned[beg + i] = stage[i];  // coalesced
}

// ---- build K2: per-bin total + per-bin run-placement prefix (one wave/bin) ----
__global__ __launch_bounds__(256) void k_binwave(const int* __restrict__ blkbin,
                                                 int* __restrict__ bintot,
                                                 int* __restrict__ blkpos) {
    int w = threadIdx.x >> 6, lane = threadIdx.x & 63;
    int bin = blockIdx.x * 4 + w;
    if (bin >= NBUCK) return;
    int v[PERLANE];
#pragma unroll
    for (int i = 0; i < PERLANE; ++i) v[i] = blkbin[bin * NBLK + lane * PERLANE + i];
    int mysum = 0;
#pragma unroll
    for (int i = 0; i < PERLANE; ++i) mysum += v[i];
    int pre = mysum;
#pragma unroll
    for (int o = 1; o < 64; o <<= 1) {
        int t = __shfl_up(pre, o);
        if (lane >= o) pre += t;
    }
    int excl = pre - mysum;
    int run = excl;
#pragma unroll
    for (int i = 0; i < PERLANE; ++i) {
        blkpos[bin * NBLK + lane * PERLANE + i] = run;
        run += v[i];
    }
    if (lane == 63) bintot[bin] = pre;
}

// ---- build K3: per-bucket 1024-key sort (dst_local*4 + src_quad) ----
// Computes its own bucket offset from bintot (binscan folded in).
__global__ __launch_bounds__(512) void k_sortdeg(const int* __restrict__ binned,
                                                 const int* __restrict__ blkbin,
                                                 const int* __restrict__ blkpos,
                                                 const int* __restrict__ locoff,
                                                 const int* __restrict__ bintot,
                                                 int* __restrict__ csr_src,
                                                 int* __restrict__ rowptr,
                                                 float* __restrict__ dinv) {
    __shared__ int stage[SCAP];      // 32 KB
    __shared__ int runlen[NBLK];     // 4 KB
    __shared__ int runpos[NBLK];     // 4 KB
    __shared__ int cnt[1024];        // 4 KB
    __shared__ int sc[1024];         // 4 KB
    __shared__ int cur[1024];        // 4 KB
    __shared__ int bs[512];          // 2 KB
    int t = threadIdx.x;
    int b = blockIdx.x;

    // inline binscan: beg = sum(bintot[0..b)), end = beg + bintot[b]
    int part = 0;
    for (int i = t; i < b; i += 512) part += bintot[i];
    bs[t] = part;
    __syncthreads();
#pragma unroll
    for (int s = 256; s > 0; s >>= 1) {
        if (t < s) bs[t] += bs[t + s];
        __syncthreads();
    }
    int beg = bs[0];
    int end = beg + bintot[b];
    int total = end - beg;
    bool fits = (total <= SCAP);

    runlen[t]       = blkbin[b * NBLK + t];
    runlen[t + 512] = blkbin[b * NBLK + t + 512];
    runpos[t]       = blkpos[b * NBLK + t];
    runpos[t + 512] = blkpos[b * NBLK + t + 512];
    cnt[t] = 0; cnt[t + 512] = 0;
    __syncthreads();

    if (fits) {
        for (int blk = t; blk < NBLK; blk += 512) {
            int len = runlen[blk];
            int srcp = locoff[blk * NBUCK + b];
            int dstp = runpos[blk];
            for (int i = 0; i < len; ++i) stage[dstp + i] = binned[srcp + i];
        }
        __syncthreads();
        for (int k = t; k < total; k += 512) {
            int p = stage[k];
            int key = ((p & 255) << 2) | ((p >> 8) / QDIV);
            atomicAdd(&cnt[key], 1);
        }
    } else {   // overflow fallback (statistically never)
        for (int blk = t; blk < NBLK; blk += 512) {
            int len = runlen[blk];
            int srcp = locoff[blk * NBUCK + b];
            for (int i = 0; i < len; ++i) {
                int p = binned[srcp + i];
                int key = ((p & 255) << 2) | ((p >> 8) / QDIV);
                atomicAdd(&cnt[key], 1);
            }
        }
    }
    __syncthreads();

    // exclusive scan over 1024 keys (2 slots/thread Hillis-Steele)
    sc[t] = cnt[t]; sc[t + 512] = cnt[t + 512];
    __syncthreads();
#pragma unroll
    for (int o = 1; o < 1024; o <<= 1) {
        int a0 = (t >= o) ? sc[t - o] : 0;
        int a1 = (t + 512 >= o) ? sc[t + 512 - o] : 0;
        __syncthreads();
        sc[t] += a0; sc[t + 512] += a1;
        __syncthreads();
    }
#pragma unroll
    for (int slot = 0; slot < 2; ++slot) {
        int k = t + slot * 512;
        int excl = sc[k] - cnt[k];
        cur[k] = excl;
        if ((k & 3) == 0) {
            int dl = k >> 2;
            int n = b * BUCKET + dl;
            if (n < N_NODES) {
                rowptr[n] = beg + excl;
                int deg = sc[k + 3] - excl;          // sum of the 4 quads
                dinv[n] = rsqrtf((float)(deg + 1));  // +1 self-loop
            }
        }
    }
    if (b == NBUCK - 1 && t == 0) rowptr[N_NODES] = end;
    __syncthreads();

    if (fits) {
        for (int k = t; k < total; k += 512) {
            int p = stage[k];
            int key = ((p & 255) << 2) | ((p >> 8) / QDIV);
            int pos = atomicAdd(&cur[key], 1);
            csr_src[beg + pos] = p >> 8;
        }
    } else {
        for (int blk = t; blk < NBLK; blk += 512) {
            int len = runlen[blk];
            int srcp = locoff[blk * NBUCK + b];
            for (int i = 0; i < len; ++i) {
                int p = binned[srcp + i];
                int key = ((p & 255) << 2) | ((p >> 8) / QDIV);
                int pos = atomicAdd(&cur[key], 1);
                csr_src[beg + pos] = p >> 8;
            }
        }
    }
}

// ================= dense helpers =================
__device__ inline void store_half8(__half* p, const float* v) {
    __half2 h[4];
#pragma unroll
    for (int i = 0; i < 4; ++i)
        h[i] = __floats2half2_rn(v[2 * i], v[2 * i + 1]);
    *(float4*)p = *(float4*)h;
}

__device__ inline void acc_half8(float* acc, float4 raw) {
    __half2* hp = (__half2*)&raw;
#pragma unroll
    for (int i = 0; i < 4; ++i) {
        float2 f = __half22float2(hp[i]);
        acc[2 * i]     += f.x;
        acc[2 * i + 1] += f.y;
    }
}

// t = relu(x@Wfc1 + bfc1); g = half( dinv * (t@Wc1) )
__global__ __launch_bounds__(256) void k_fc1_conv1(
        const float* __restrict__ x,
        const float* __restrict__ Wfc1, const float* __restrict__ bfc1,
        const float* __restrict__ Wc1, const float* __restrict__ dinv,
        __half* __restrict__ g) {
    __shared__ float  sWf[128];
    __shared__ float  sbf[32];
    __shared__ float4 sW[256];
    if (threadIdx.x < 128) sWf[threadIdx.x] = Wfc1[threadIdx.x];
    if (threadIdx.x < 32)  sbf[threadIdx.x] = bfc1[threadIdx.x];
    sW[threadIdx.x] = ((const float4*)Wc1)[threadIdx.x];
    __syncthreads();

    int n = blockIdx.x * 256 + threadIdx.x;
    if (n >= N_NODES) return;

    float4 xin = *(const float4*)(x + (size_t)n * 4);
    float t[32];
#pragma unroll
    for (int j = 0; j < 32; ++j) {
        float a = fmaf(xin.x, sWf[j], sbf[j]);
        a = fmaf(xin.y, sWf[32 + j], a);
        a = fmaf(xin.z, sWf[64 + j], a);
        a = fmaf(xin.w, sWf[96 + j], a);
        t[j] = fmaxf(a, 0.0f);
    }
    float o[32];
#pragma unroll
    for (int j = 0; j < 32; ++j) o[j] = 0.f;
#pragma unroll
    for (int k = 0; k < 32; ++k) {
        float a = t[k];
#pragma unroll
        for (int q = 0; q < 8; ++q) {
            float4 w = sW[k * 8 + q];
            o[q * 4 + 0] = fmaf(a, w.x, o[q * 4 + 0]);
            o[q * 4 + 1] = fmaf(a, w.y, o[q * 4 + 1]);
            o[q * 4 + 2] = fmaf(a, w.z, o[q * 4 + 2]);
            o[q * 4 + 3] = fmaf(a, w.w, o[q * 4 + 3]);
        }
    }
    float dv = dinv[n];
#pragma unroll
    for (int j = 0; j < 32; ++j) o[j] *= dv;
    __half* gp = g + (size_t)n * 32;
    store_half8(gp,      o);
    store_half8(gp + 8,  o + 8);
    store_half8(gp + 16, o + 16);
    store_half8(gp + 24, o + 24);
}

// ---- edge accumulate: software-pipelined (prefetch next 4 indices) ----
// csr is quad-sorted within each node, so a single linear walk IS the
// soft-phased traversal (no per-segment pipeline breaks).
__device__ inline void gather_seg(int beg, int end, const int* __restrict__ csr_src,
                                  const __half* __restrict__ gin, int sub, float* acc) {
    int k = beg;
    int stop = beg + ((end - beg) & ~3);
    if (k < stop) {
        int s0 = csr_src[k], s1 = csr_src[k + 1];
        int s2 = csr_src[k + 2], s3 = csr_src[k + 3];
        k += 4;
        while (k < stop) {
            float4 r0 = *(const float4*)(gin + (size_t)s0 * 32 + sub * 8);
            float4 r1 = *(const float4*)(gin + (size_t)s1 * 32 + sub * 8);
            float4 r2 = *(const float4*)(gin + (size_t)s2 * 32 + sub * 8);
            float4 r3 = *(const float4*)(gin + (size_t)s3 * 32 + sub * 8);
            s0 = csr_src[k]; s1 = csr_src[k + 1];
            s2 = csr_src[k + 2]; s3 = csr_src[k + 3];
            acc_half8(acc, r0); acc_half8(acc, r1);
            acc_half8(acc, r2); acc_half8(acc, r3);
            k += 4;
        }
        float4 r0 = *(const float4*)(gin + (size_t)s0 * 32 + sub * 8);
        float4 r1 = *(const float4*)(gin + (size_t)s1 * 32 + sub * 8);
        float4 r2 = *(const float4*)(gin + (size_t)s2 * 32 + sub * 8);
        float4 r3 = *(const float4*)(gin + (size_t)s3 * 32 + sub * 8);
        acc_half8(acc, r0); acc_half8(acc, r1);
        acc_half8(acc, r2); acc_half8(acc, r3);
    }
    for (; k < end; ++k) {
        int s = csr_src[k];
        float4 r = *(const float4*)(gin + (size_t)s * 32 + sub * 8);
        acc_half8(acc, r);
    }
}

// ---- soft-phased fused gather + mid MLP: 4 threads/node, 64 nodes/block ----
__global__ __launch_bounds__(256) void k_gather_mid(
        const int* __restrict__ rowptr,
        const int* __restrict__ csr_src, const __half* __restrict__ gin,
        const float* __restrict__ dinv,
        const float* __restrict__ b, const float* __restrict__ W,
        __half* __restrict__ gout) {
    __shared__ float sS[64 * 33];
    __shared__ float sW[1024];
    __shared__ float sb[32];
    for (int i = threadIdx.x; i < 1024; i += 256) sW[i] = W[i];
    if (threadIdx.x < 32) sb[threadIdx.x] = b[threadIdx.x];

    int nl = threadIdx.x >> 2;
    int sub = threadIdx.x & 3;
    int n = blockIdx.x * 64 + nl;
    float acc[8];
    if (n < N_NODES) {
        float4 self = *(const float4*)(gin + (size_t)n * 32 + sub * 8);
        {
            __half2* hp = (__half2*)&self;
#pragma unroll
            for (int i = 0; i < 4; ++i) {
                float2 f = __half22float2(hp[i]);
                acc[2 * i] = f.x;
                acc[2 * i + 1] = f.y;
            }
        }
        gather_seg(rowptr[n], rowptr[n + 1], csr_src, gin, sub, acc);
#pragma unroll
        for (int i = 0; i < 8; ++i) sS[nl * 33 + sub * 8 + i] = acc[i];
    }
    __syncthreads();

    if (n >= N_NODES) return;
    float dv = dinv[n];
    float t[32];
#pragma unroll
    for (int kk = 0; kk < 32; ++kk)
        t[kk] = fmaxf(fmaf(dv, sS[nl * 33 + kk], sb[kk]), 0.0f);
    float o[8];
#pragma unroll
    for (int j = 0; j < 8; ++j) o[j] = 0.f;
#pragma unroll
    for (int kk = 0; kk < 32; ++kk) {
        float a = t[kk];
#pragma unroll
        for (int j = 0; j < 8; ++j)
            o[j] = fmaf(a, sW[kk * 32 + sub * 8 + j], o[j]);
    }
#pragma unroll
    for (int j = 0; j < 8; ++j) o[j] *= dv;
    store_half8(gout + (size_t)n * 32 + sub * 8, o);
}

// ---- soft-phased fused gather + final layer ----
__global__ __launch_bounds__(256) void k_gather_out(
        const int* __restrict__ rowptr,
        const int* __restrict__ csr_src, const __half* __restrict__ gin,
        const float* __restrict__ dinv,
        const float* __restrict__ bc3, const float* __restrict__ Wfc2,
        const float* __restrict__ bfc2, float* __restrict__ out) {
    __shared__ float sS[64 * 33];
    __shared__ float sW[96];
    __shared__ float sb[32];
    __shared__ float sb2[3];
    if (threadIdx.x < 96) sW[threadIdx.x] = Wfc2[threadIdx.x];
    if (threadIdx.x < 32) sb[threadIdx.x] = bc3[threadIdx.x];
    if (threadIdx.x < 3)  sb2[threadIdx.x] = bfc2[threadIdx.x];

    int nl = threadIdx.x >> 2;
    int sub = threadIdx.x & 3;
    int n = blockIdx.x * 64 + nl;
    float acc[8];
    if (n < N_NODES) {
        float4 self = *(const float4*)(gin + (size_t)n * 32 + sub * 8);
        {
            __half2* hp = (__half2*)&self;
#pragma unroll
            for (int i = 0; i < 4; ++i) {
                float2 f = __half22float2(hp[i]);
                acc[2 * i] = f.x;
                acc[2 * i + 1] = f.y;
            }
        }
        gather_seg(rowptr[n], rowptr[n + 1], csr_src, gin, sub, acc);
#pragma unroll
        for (int i = 0; i < 8; ++i) sS[nl * 33 + sub * 8 + i] = acc[i];
    }
    __syncthreads();

    if (n >= N_NODES || sub != 0) return;
    float dv = dinv[n];
    float t[32];
#pragma unroll
    for (int kk = 0; kk < 32; ++kk)
        t[kk] = fmaxf(fmaf(dv, sS[nl * 33 + kk], sb[kk]), 0.0f);
    float o0 = sb2[0], o1 = sb2[1], o2 = sb2[2];
#pragma unroll
    for (int kk = 0; kk < 32; ++kk) {
        o0 = fmaf(t[kk], sW[kk * 3 + 0], o0);
        o1 = fmaf(t[kk], sW[kk * 3 + 1], o1);
        o2 = fmaf(t[kk], sW[kk * 3 + 2], o2);
    }
    out[(size_t)n * 3 + 0] = o0;
    out[(size_t)n * 3 + 1] = o1;
    out[(size_t)n * 3 + 2] = o2;
}

extern "C" void kernel_launch(void* const* d_in, const int* in_sizes, int n_in,
                              void* d_out, int out_size, void* d_ws, size_t ws_size,
                              hipStream_t stream) {
    const float* x    = (const float*)d_in[0];
    const int*   ei   = (const int*)d_in[1];
    const float* Wfc1 = (const float*)d_in[2];
    const float* bfc1 = (const float*)d_in[3];
    const float* Wc1  = (const float*)d_in[4];
    const float* bc1  = (const float*)d_in[5];
    const float* Wc2  = (const float*)d_in[6];
    const float* bc2  = (const float*)d_in[7];
    const float* Wc3  = (const float*)d_in[8];
    const float* bc3  = (const float*)d_in[9];
    const float* Wfc2 = (const float*)d_in[10];
    const float* bfc2 = (const float*)d_in[11];
    float* out = (float*)d_out;

    char* ws = (char*)d_ws;
    const size_t grow = (size_t)N_NODES * 32 * sizeof(__half);   // 6.4 MB
    size_t off = 0;
    __half* gA     = (__half*)(ws + off); off += grow;
    __half* gB     = (__half*)(ws + off); off += grow;
    int*   binned  = (int*)  (ws + off); off += (size_t)NBLK * CHUNK * sizeof(int);
    int*   csr_src = (int*)  (ws + off); off += (size_t)N_EDGES * sizeof(int);
    float* dinv    = (float*)(ws + off); off += (size_t)N_NODES * sizeof(float);
    int*   rowptr  = (int*)  (ws + off); off += (size_t)(N_NODES + 1) * sizeof(int);
    int*   blkbin  = (int*)  (ws + off); off += (size_t)NBUCK * NBLK * sizeof(int);
    int*   blkpos  = (int*)  (ws + off); off += (size_t)NBUCK * NBLK * sizeof(int);
    int*   locoff  = (int*)  (ws + off); off += (size_t)NBLK * NBUCK * sizeof(int);
    int*   bintot  = (int*)  (ws + off); off += (size_t)NBUCK * sizeof(int);

    const int nb_wave = (NBUCK + 3) / 4;              // 98
    const int nb_n = (N_NODES + 255) / 256;           // 391
    const int nb_f = (N_NODES * 4 + 255) / 256;       // 1563 (4 thr/node)

    k_binfill<<<NBLK, 256, 0, stream>>>(ei, binned, blkbin, locoff);
    k_binwave<<<nb_wave, 256, 0, stream>>>(blkbin, bintot, blkpos);
    k_sortdeg<<<NBUCK, 512, 0, stream>>>(binned, blkbin, blkpos, locoff, bintot,
                                         csr_src, rowptr, dinv);

    k_fc1_conv1<<<nb_n, 256, 0, stream>>>(x, Wfc1, bfc1, Wc1, dinv, gA);
    k_gather_mid<<<nb_f, 256, 0, stream>>>(rowptr, csr_src, gA, dinv, bc1, Wc2, gB);
    k_gather_mid<<<nb_f, 256, 0, stream>>>(rowptr, csr_src, gB, dinv, bc2, Wc3, gA);
    k_gather_out<<<nb_f, 256, 0, stream>>>(rowptr, csr_src, gA, dinv, bc3, Wfc2, bfc2, out);
}

// Round 15
// 221.927 us; speedup vs baseline: 1.0548x; 1.0548x over previous
//
#include <hip/hip_runtime.h>
#include <hip/hip_fp16.h>

// GCN: 100K nodes, 2.5M edges, dims 4 -> 32 -> (32x32 conv x3) -> 3.
// Round 15: (a) REVERT gather to R13's per-segment walk. R14's fused loop
// regressed (227->234): the per-segment calls are wave-level phase barriers
// (SIMT lockstep keeps all nodes in a wave on the same quad), which is what
// makes the soft-phase L2 hot-set work. (b) NBLK 1024->512: sortdeg's run
// assembly had ~2.7x read amplification at 6-edge runs (<1 line); 12-edge
// runs cut that to ~1.6x and halve run-table traffic. binfill stays 2
// blocks/CU (stage 19.5KB). Keep R14's folded binscan.

constexpr int N_NODES = 100000;
constexpr int N_EDGES = 2500000;
constexpr int QDIV    = 25000;                             // src quad divisor
constexpr int BUCKET  = 256;
constexpr int NBUCK   = (N_NODES + BUCKET - 1) / BUCKET;   // 391
constexpr int NBLK    = 512;                               // build blocks
constexpr int CHUNK   = (N_EDGES + NBLK - 1) / NBLK;       // 4883
constexpr int SCAP    = 8192;                              // sortdeg LDS stage cap
constexpr int PERLANE = NBLK / 64;                         // 8

// ---- build K1: per-block LDS counting sort by bucket; contiguous write ----
__global__ __launch_bounds__(256) void k_binfill(const int* __restrict__ ei,
                                                 int* __restrict__ binned,
                                                 int* __restrict__ blkbin,
                                                 int* __restrict__ locoff) {
    __shared__ int cnt[NBUCK];
    __shared__ int cur[NBUCK];
    __shared__ int sc[512];
    __shared__ int stage[CHUNK];
    int tid = threadIdx.x;
    int blk = blockIdx.x;
    int beg = blk * CHUNK;
    int end = min(beg + CHUNK, N_EDGES);
    int m = end - beg;

    for (int i = tid; i < NBUCK; i += 256) cnt[i] = 0;
    __syncthreads();
    for (int e = beg + tid; e < end; e += 256)
        atomicAdd(&cnt[ei[N_EDGES + e] >> 8], 1);
    __syncthreads();

    sc[tid]       = (tid < NBUCK) ? cnt[tid] : 0;
    sc[tid + 256] = (tid + 256 < NBUCK) ? cnt[tid + 256] : 0;
    __syncthreads();
#pragma unroll
    for (int o = 1; o < 512; o <<= 1) {
        int a0 = (tid >= o) ? sc[tid - o] : 0;
        int a1 = (tid + 256 >= o) ? sc[tid + 256 - o] : 0;
        __syncthreads();
        sc[tid] += a0; sc[tid + 256] += a1;
        __syncthreads();
    }
    if (tid < NBUCK) {
        int excl = sc[tid] - cnt[tid];
        cur[tid] = excl;
        blkbin[tid * NBLK + blk] = cnt[tid];
        locoff[blk * NBUCK + tid] = beg + excl;
    }
    if (tid + 256 < NBUCK) {
        int i = tid + 256;
        int excl = sc[i] - cnt[i];
        cur[i] = excl;
        blkbin[i * NBLK + blk] = cnt[i];
        locoff[blk * NBUCK + i] = beg + excl;
    }
    __syncthreads();

    for (int e = beg + tid; e < end; e += 256) {
        int s = ei[e];
        int d = ei[N_EDGES + e];
        int pos = atomicAdd(&cur[d >> 8], 1);
        stage[pos] = (s << 8) | (d & 255);     // src<17b><<8 | dst_local<8b>
    }
    __syncthreads();
    for (int i = tid; i < m; i += 256) binned[beg + i] = stage[i];  // coalesced
}

// ---- build K2: per-bin total + per-bin run-placement prefix (one wave/bin) ----
__global__ __launch_bounds__(256) void k_binwave(const int* __restrict__ blkbin,
                                                 int* __restrict__ bintot,
                                                 int* __restrict__ blkpos) {
    int w = threadIdx.x >> 6, lane = threadIdx.x & 63;
    int bin = blockIdx.x * 4 + w;
    if (bin >= NBUCK) return;
    int v[PERLANE];
#pragma unroll
    for (int i = 0; i < PERLANE; ++i) v[i] = blkbin[bin * NBLK + lane * PERLANE + i];
    int mysum = 0;
#pragma unroll
    for (int i = 0; i < PERLANE; ++i) mysum += v[i];
    int pre = mysum;
#pragma unroll
    for (int o = 1; o < 64; o <<= 1) {
        int t = __shfl_up(pre, o);
        if (lane >= o) pre += t;
    }
    int excl = pre - mysum;
    int run = excl;
#pragma unroll
    for (int i = 0; i < PERLANE; ++i) {
        blkpos[bin * NBLK + lane * PERLANE + i] = run;
        run += v[i];
    }
    if (lane == 63) bintot[bin] = pre;
}

// ---- build K3: per-bucket 1024-key sort (dst_local*4 + src_quad) ----
// Computes its own bucket offset from bintot (binscan folded in).
__global__ __launch_bounds__(512) void k_sortdeg(const int* __restrict__ binned,
                                                 const int* __restrict__ blkbin,
                                                 const int* __restrict__ blkpos,
                                                 const int* __restrict__ locoff,
                                                 const int* __restrict__ bintot,
                                                 int* __restrict__ csr_src,
                                                 int* __restrict__ rowseg,
                                                 float* __restrict__ dinv) {
    __shared__ int stage[SCAP];      // 32 KB
    __shared__ int runlen[NBLK];     // 2 KB
    __shared__ int runpos[NBLK];     // 2 KB
    __shared__ int cnt[1024];        // 4 KB
    __shared__ int sc[1024];         // 4 KB
    __shared__ int cur[1024];        // 4 KB
    __shared__ int bs[512];          // 2 KB
    int t = threadIdx.x;
    int b = blockIdx.x;

    // inline binscan: beg = sum(bintot[0..b)), end = beg + bintot[b]
    int part = 0;
    for (int i = t; i < b; i += 512) part += bintot[i];
    bs[t] = part;
    __syncthreads();
#pragma unroll
    for (int s = 256; s > 0; s >>= 1) {
        if (t < s) bs[t] += bs[t + s];
        __syncthreads();
    }
    int beg = bs[0];
    int end = beg + bintot[b];
    int total = end - beg;
    bool fits = (total <= SCAP);

    if (t < NBLK) {
        runlen[t] = blkbin[b * NBLK + t];
        runpos[t] = blkpos[b * NBLK + t];
    }
    cnt[t] = 0; cnt[t + 512] = 0;
    __syncthreads();

    if (fits) {
        for (int blk = t; blk < NBLK; blk += 512) {
            int len = runlen[blk];
            int srcp = locoff[blk * NBUCK + b];
            int dstp = runpos[blk];
            for (int i = 0; i < len; ++i) stage[dstp + i] = binned[srcp + i];
        }
        __syncthreads();
        for (int k = t; k < total; k += 512) {
            int p = stage[k];
            int key = ((p & 255) << 2) | ((p >> 8) / QDIV);
            atomicAdd(&cnt[key], 1);
        }
    } else {   // overflow fallback (statistically never)
        for (int blk = t; blk < NBLK; blk += 512) {
            int len = runlen[blk];
            int srcp = locoff[blk * NBUCK + b];
            for (int i = 0; i < len; ++i) {
                int p = binned[srcp + i];
                int key = ((p & 255) << 2) | ((p >> 8) / QDIV);
                atomicAdd(&cnt[key], 1);
            }
        }
    }
    __syncthreads();

    // exclusive scan over 1024 keys (2 slots/thread Hillis-Steele)
    sc[t] = cnt[t]; sc[t + 512] = cnt[t + 512];
    __syncthreads();
#pragma unroll
    for (int o = 1; o < 1024; o <<= 1) {
        int a0 = (t >= o) ? sc[t - o] : 0;
        int a1 = (t + 512 >= o) ? sc[t + 512 - o] : 0;
        __syncthreads();
        sc[t] += a0; sc[t + 512] += a1;
        __syncthreads();
    }
#pragma unroll
    for (int slot = 0; slot < 2; ++slot) {
        int k = t + slot * 512;
        int excl = sc[k] - cnt[k];
        cur[k] = excl;
        int dl = k >> 2, q = k & 3;
        int n = b * BUCKET + dl;
        if (n < N_NODES) {
            rowseg[n * 4 + q] = beg + excl;
            if (q == 0) {
                int deg = sc[k + 3] - excl;          // sum of the 4 quads
                dinv[n] = rsqrtf((float)(deg + 1));  // +1 self-loop
            }
        }
    }
    if (b == NBUCK - 1 && t == 0) rowseg[(size_t)N_NODES * 4] = end;  // sentinel
    __syncthreads();

    if (fits) {
        for (int k = t; k < total; k += 512) {
            int p = stage[k];
            int key = ((p & 255) << 2) | ((p >> 8) / QDIV);
            int pos = atomicAdd(&cur[key], 1);
            csr_src[beg + pos] = p >> 8;
        }
    } else {
        for (int blk = t; blk < NBLK; blk += 512) {
            int len = runlen[blk];
            int srcp = locoff[blk * NBUCK + b];
            for (int i = 0; i < len; ++i) {
                int p = binned[srcp + i];
                int key = ((p & 255) << 2) | ((p >> 8) / QDIV);
                int pos = atomicAdd(&cur[key], 1);
                csr_src[beg + pos] = p >> 8;
            }
        }
    }
}

// ================= dense helpers =================
__device__ inline void store_half8(__half* p, const float* v) {
    __half2 h[4];
#pragma unroll
    for (int i = 0; i < 4; ++i)
        h[i] = __floats2half2_rn(v[2 * i], v[2 * i + 1]);
    *(float4*)p = *(float4*)h;
}

__device__ inline void acc_half8(float* acc, float4 raw) {
    __half2* hp = (__half2*)&raw;
#pragma unroll
    for (int i = 0; i < 4; ++i) {
        float2 f = __half22float2(hp[i]);
        acc[2 * i]     += f.x;
        acc[2 * i + 1] += f.y;
    }
}

// t = relu(x@Wfc1 + bfc1); g = half( dinv * (t@Wc1) )
__global__ __launch_bounds__(256) void k_fc1_conv1(
        const float* __restrict__ x,
        const float* __restrict__ Wfc1, const float* __restrict__ bfc1,
        const float* __restrict__ Wc1, const float* __restrict__ dinv,
        __half* __restrict__ g) {
    __shared__ float  sWf[128];
    __shared__ float  sbf[32];
    __shared__ float4 sW[256];
    if (threadIdx.x < 128) sWf[threadIdx.x] = Wfc1[threadIdx.x];
    if (threadIdx.x < 32)  sbf[threadIdx.x] = bfc1[threadIdx.x];
    sW[threadIdx.x] = ((const float4*)Wc1)[threadIdx.x];
    __syncthreads();

    int n = blockIdx.x * 256 + threadIdx.x;
    if (n >= N_NODES) return;

    float4 xin = *(const float4*)(x + (size_t)n * 4);
    float t[32];
#pragma unroll
    for (int j = 0; j < 32; ++j) {
        float a = fmaf(xin.x, sWf[j], sbf[j]);
        a = fmaf(xin.y, sWf[32 + j], a);
        a = fmaf(xin.z, sWf[64 + j], a);
        a = fmaf(xin.w, sWf[96 + j], a);
        t[j] = fmaxf(a, 0.0f);
    }
    float o[32];
#pragma unroll
    for (int j = 0; j < 32; ++j) o[j] = 0.f;
#pragma unroll
    for (int k = 0; k < 32; ++k) {
        float a = t[k];
#pragma unroll
        for (int q = 0; q < 8; ++q) {
            float4 w = sW[k * 8 + q];
            o[q * 4 + 0] = fmaf(a, w.x, o[q * 4 + 0]);
            o[q * 4 + 1] = fmaf(a, w.y, o[q * 4 + 1]);
            o[q * 4 + 2] = fmaf(a, w.z, o[q * 4 + 2]);
            o[q * 4 + 3] = fmaf(a, w.w, o[q * 4 + 3]);
        }
    }
    float dv = dinv[n];
#pragma unroll
    for (int j = 0; j < 32; ++j) o[j] *= dv;
    __half* gp = g + (size_t)n * 32;
    store_half8(gp,      o);
    store_half8(gp + 8,  o + 8);
    store_half8(gp + 16, o + 16);
    store_half8(gp + 24, o + 24);
}

// ---- edge-segment accumulate: software-pipelined (prefetch next 4 indices) ----
__device__ inline void gather_seg(int beg, int end, const int* __restrict__ csr_src,
                                  const __half* __restrict__ gin, int sub, float* acc) {
    int k = beg;
    int stop = beg + ((end - beg) & ~3);
    if (k < stop) {
        int s0 = csr_src[k], s1 = csr_src[k + 1];
        int s2 = csr_src[k + 2], s3 = csr_src[k + 3];
        k += 4;
        while (k < stop) {
            float4 r0 = *(const float4*)(gin + (size_t)s0 * 32 + sub * 8);
            float4 r1 = *(const float4*)(gin + (size_t)s1 * 32 + sub * 8);
            float4 r2 = *(const float4*)(gin + (size_t)s2 * 32 + sub * 8);
            float4 r3 = *(const float4*)(gin + (size_t)s3 * 32 + sub * 8);
            s0 = csr_src[k]; s1 = csr_src[k + 1];
            s2 = csr_src[k + 2]; s3 = csr_src[k + 3];
            acc_half8(acc, r0); acc_half8(acc, r1);
            acc_half8(acc, r2); acc_half8(acc, r3);
            k += 4;
        }
        float4 r0 = *(const float4*)(gin + (size_t)s0 * 32 + sub * 8);
        float4 r1 = *(const float4*)(gin + (size_t)s1 * 32 + sub * 8);
        float4 r2 = *(const float4*)(gin + (size_t)s2 * 32 + sub * 8);
        float4 r3 = *(const float4*)(gin + (size_t)s3 * 32 + sub * 8);
        acc_half8(acc, r0); acc_half8(acc, r1);
        acc_half8(acc, r2); acc_half8(acc, r3);
    }
    for (; k < end; ++k) {
        int s = csr_src[k];
        float4 r = *(const float4*)(gin + (size_t)s * 32 + sub * 8);
        acc_half8(acc, r);
    }
}

// ---- 4-phase soft gather + mid MLP: 4 threads/node, 64 nodes/block ----
// Per-segment calls act as wave-level phase barriers (SIMT lockstep).
__global__ __launch_bounds__(256) void k_gather_mid(
        const int* __restrict__ rowseg,
        const int* __restrict__ csr_src, const __half* __restrict__ gin,
        const float* __restrict__ dinv,
        const float* __restrict__ b, const float* __restrict__ W,
        __half* __restrict__ gout) {
    __shared__ float sS[64 * 33];
    __shared__ float sW[1024];
    __shared__ float sb[32];
    for (int i = threadIdx.x; i < 1024; i += 256) sW[i] = W[i];
    if (threadIdx.x < 32) sb[threadIdx.x] = b[threadIdx.x];

    int nl = threadIdx.x >> 2;
    int sub = threadIdx.x & 3;
    int n = blockIdx.x * 64 + nl;
    float acc[8];
    if (n < N_NODES) {
        float4 self = *(const float4*)(gin + (size_t)n * 32 + sub * 8);
        {
            __half2* hp = (__half2*)&self;
#pragma unroll
            for (int i = 0; i < 4; ++i) {
                float2 f = __half22float2(hp[i]);
                acc[2 * i] = f.x;
                acc[2 * i + 1] = f.y;
            }
        }
        int4 seg = *(const int4*)(rowseg + (size_t)n * 4);
        int segend = rowseg[(size_t)n * 4 + 4];          // next start / sentinel
        gather_seg(seg.x, seg.y, csr_src, gin, sub, acc);   // quad 0
        gather_seg(seg.y, seg.z, csr_src, gin, sub, acc);   // quad 1
        gather_seg(seg.z, seg.w, csr_src, gin, sub, acc);   // quad 2
        gather_seg(seg.w, segend, csr_src, gin, sub, acc);  // quad 3
#pragma unroll
        for (int i = 0; i < 8; ++i) sS[nl * 33 + sub * 8 + i] = acc[i];
    }
    __syncthreads();

    if (n >= N_NODES) return;
    float dv = dinv[n];
    float t[32];
#pragma unroll
    for (int kk = 0; kk < 32; ++kk)
        t[kk] = fmaxf(fmaf(dv, sS[nl * 33 + kk], sb[kk]), 0.0f);
    float o[8];
#pragma unroll
    for (int j = 0; j < 8; ++j) o[j] = 0.f;
#pragma unroll
    for (int kk = 0; kk < 32; ++kk) {
        float a = t[kk];
#pragma unroll
        for (int j = 0; j < 8; ++j)
            o[j] = fmaf(a, sW[kk * 32 + sub * 8 + j], o[j]);
    }
#pragma unroll
    for (int j = 0; j < 8; ++j) o[j] *= dv;
    store_half8(gout + (size_t)n * 32 + sub * 8, o);
}

// ---- 4-phase soft gather + final layer ----
__global__ __launch_bounds__(256) void k_gather_out(
        const int* __restrict__ rowseg,
        const int* __restrict__ csr_src, const __half* __restrict__ gin,
        const float* __restrict__ dinv,
        const float* __restrict__ bc3, const float* __restrict__ Wfc2,
        const float* __restrict__ bfc2, float* __restrict__ out) {
    __shared__ float sS[64 * 33];
    __shared__ float sW[96];
    __shared__ float sb[32];
    __shared__ float sb2[3];
    if (threadIdx.x < 96) sW[threadIdx.x] = Wfc2[threadIdx.x];
    if (threadIdx.x < 32) sb[threadIdx.x] = bc3[threadIdx.x];
    if (threadIdx.x < 3)  sb2[threadIdx.x] = bfc2[threadIdx.x];

    int nl = threadIdx.x >> 2;
    int sub = threadIdx.x & 3;
    int n = blockIdx.x * 64 + nl;
    float acc[8];
    if (n < N_NODES) {
        float4 self = *(const float4*)(gin + (size_t)n * 32 + sub * 8);
        {
            __half2* hp = (__half2*)&self;
#pragma unroll
            for (int i = 0; i < 4; ++i) {
                float2 f = __half22float2(hp[i]);
                acc[2 * i] = f.x;
                acc[2 * i + 1] = f.y;
            }
        }
        int4 seg = *(const int4*)(rowseg + (size_t)n * 4);
        int segend = rowseg[(size_t)n * 4 + 4];
        gather_seg(seg.x, seg.y, csr_src, gin, sub, acc);
        gather_seg(seg.y, seg.z, csr_src, gin, sub, acc);
        gather_seg(seg.z, seg.w, csr_src, gin, sub, acc);
        gather_seg(seg.w, segend, csr_src, gin, sub, acc);
#pragma unroll
        for (int i = 0; i < 8; ++i) sS[nl * 33 + sub * 8 + i] = acc[i];
    }
    __syncthreads();

    if (n >= N_NODES || sub != 0) return;
    float dv = dinv[n];
    float t[32];
#pragma unroll
    for (int kk = 0; kk < 32; ++kk)
        t[kk] = fmaxf(fmaf(dv, sS[nl * 33 + kk], sb[kk]), 0.0f);
    float o0 = sb2[0], o1 = sb2[1], o2 = sb2[2];
#pragma unroll
    for (int kk = 0; kk < 32; ++kk) {
        o0 = fmaf(t[kk], sW[kk * 3 + 0], o0);
        o1 = fmaf(t[kk], sW[kk * 3 + 1], o1);
        o2 = fmaf(t[kk], sW[kk * 3 + 2], o2);
    }
    out[(size_t)n * 3 + 0] = o0;
    out[(size_t)n * 3 + 1] = o1;
    out[(size_t)n * 3 + 2] = o2;
}

extern "C" void kernel_launch(void* const* d_in, const int* in_sizes, int n_in,
                              void* d_out, int out_size, void* d_ws, size_t ws_size,
                              hipStream_t stream) {
    const float* x    = (const float*)d_in[0];
    const int*   ei   = (const int*)d_in[1];
    const float* Wfc1 = (const float*)d_in[2];
    const float* bfc1 = (const float*)d_in[3];
    const float* Wc1  = (const float*)d_in[4];
    const float* bc1  = (const float*)d_in[5];
    const float* Wc2  = (const float*)d_in[6];
    const float* bc2  = (const float*)d_in[7];
    const float* Wc3  = (const float*)d_in[8];
    const float* bc3  = (const float*)d_in[9];
    const float* Wfc2 = (const float*)d_in[10];
    const float* bfc2 = (const float*)d_in[11];
    float* out = (float*)d_out;

    char* ws = (char*)d_ws;
    const size_t grow = (size_t)N_NODES * 32 * sizeof(__half);   // 6.4 MB
    size_t off = 0;
    __half* gA     = (__half*)(ws + off); off += grow;
    __half* gB     = (__half*)(ws + off); off += grow;
    int*   binned  = (int*)  (ws + off); off += (size_t)NBLK * CHUNK * sizeof(int);
    int*   csr_src = (int*)  (ws + off); off += (size_t)N_EDGES * sizeof(int);
    float* dinv    = (float*)(ws + off); off += (size_t)N_NODES * sizeof(float);
    int*   rowseg  = (int*)  (ws + off); off += ((size_t)N_NODES * 4 + 16) * sizeof(int);
    int*   blkbin  = (int*)  (ws + off); off += (size_t)NBUCK * NBLK * sizeof(int);
    int*   blkpos  = (int*)  (ws + off); off += (size_t)NBUCK * NBLK * sizeof(int);
    int*   locoff  = (int*)  (ws + off); off += (size_t)NBLK * NBUCK * sizeof(int);
    int*   bintot  = (int*)  (ws + off); off += (size_t)NBUCK * sizeof(int);

    const int nb_wave = (NBUCK + 3) / 4;              // 98
    const int nb_n = (N_NODES + 255) / 256;           // 391
    const int nb_f = (N_NODES * 4 + 255) / 256;       // 1563 (4 thr/node)

    k_binfill<<<NBLK, 256, 0, stream>>>(ei, binned, blkbin, locoff);
    k_binwave<<<nb_wave, 256, 0, stream>>>(blkbin, bintot, blkpos);
    k_sortdeg<<<NBUCK, 512, 0, stream>>>(binned, blkbin, blkpos, locoff, bintot,
                                         csr_src, rowseg, dinv);

    k_fc1_conv1<<<nb_n, 256, 0, stream>>>(x, Wfc1, bfc1, Wc1, dinv, gA);
    k_gather_mid<<<nb_f, 256, 0, stream>>>(rowseg, csr_src, gA, dinv, bc1, Wc2, gB);
    k_gather_mid<<<nb_f, 256, 0, stream>>>(rowseg, csr_src, gB, dinv, bc2, Wc3, gA);
    k_gather_out<<<nb_f, 256, 0, stream>>>(rowseg, csr_src, gA, dinv, bc3, Wfc2, bfc2, out);
}

// Round 16
// 218.303 us; speedup vs baseline: 1.0723x; 1.0166x over previous
//
#include <hip/hip_runtime.h>
#include <hip/hip_fp16.h>

// GCN: 100K nodes, 2.5M edges, dims 4 -> 32 -> (32x32 conv x3) -> 3.
// Round 16: 16-BIT CSR. The quad sort bounds src offsets within a segment to
// QDIV=25000 < 64K, so csr_src becomes ushort (src - quad*QDIV); gather
// reconstructs src = quad*QDIV + off (uniform add). Index stream per gather
// 10->5MB, sortdeg scatter writes 10->5MB, and the halved stream footprint
// protects the per-quad 1.6MB g hot set in L2 (the R6/R8-verified mechanism).
// Rest = R15: 4-phase segmented gather (wave-level phase barriers), NBLK=512
// scatter-free build, folded binscan, fp16 g, fp32 accumulate.

constexpr int N_NODES = 100000;
constexpr int N_EDGES = 2500000;
constexpr int QDIV    = 25000;                             // src quad divisor
constexpr int BUCKET  = 256;
constexpr int NBUCK   = (N_NODES + BUCKET - 1) / BUCKET;   // 391
constexpr int NBLK    = 512;                               // build blocks
constexpr int CHUNK   = (N_EDGES + NBLK - 1) / NBLK;       // 4883
constexpr int SCAP    = 8192;                              // sortdeg LDS stage cap
constexpr int PERLANE = NBLK / 64;                         // 8

// ---- build K1: per-block LDS counting sort by bucket; contiguous write ----
__global__ __launch_bounds__(256) void k_binfill(const int* __restrict__ ei,
                                                 int* __restrict__ binned,
                                                 int* __restrict__ blkbin,
                                                 int* __restrict__ locoff) {
    __shared__ int cnt[NBUCK];
    __shared__ int cur[NBUCK];
    __shared__ int sc[512];
    __shared__ int stage[CHUNK];
    int tid = threadIdx.x;
    int blk = blockIdx.x;
    int beg = blk * CHUNK;
    int end = min(beg + CHUNK, N_EDGES);
    int m = end - beg;

    for (int i = tid; i < NBUCK; i += 256) cnt[i] = 0;
    __syncthreads();
    for (int e = beg + tid; e < end; e += 256)
        atomicAdd(&cnt[ei[N_EDGES + e] >> 8], 1);
    __syncthreads();

    sc[tid]       = (tid < NBUCK) ? cnt[tid] : 0;
    sc[tid + 256] = (tid + 256 < NBUCK) ? cnt[tid + 256] : 0;
    __syncthreads();
#pragma unroll
    for (int o = 1; o < 512; o <<= 1) {
        int a0 = (tid >= o) ? sc[tid - o] : 0;
        int a1 = (tid + 256 >= o) ? sc[tid + 256 - o] : 0;
        __syncthreads();
        sc[tid] += a0; sc[tid + 256] += a1;
        __syncthreads();
    }
    if (tid < NBUCK) {
        int excl = sc[tid] - cnt[tid];
        cur[tid] = excl;
        blkbin[tid * NBLK + blk] = cnt[tid];
        locoff[blk * NBUCK + tid] = beg + excl;
    }
    if (tid + 256 < NBUCK) {
        int i = tid + 256;
        int excl = sc[i] - cnt[i];
        cur[i] = excl;
        blkbin[i * NBLK + blk] = cnt[i];
        locoff[blk * NBUCK + i] = beg + excl;
    }
    __syncthreads();

    for (int e = beg + tid; e < end; e += 256) {
        int s = ei[e];
        int d = ei[N_EDGES + e];
        int pos = atomicAdd(&cur[d >> 8], 1);
        stage[pos] = (s << 8) | (d & 255);     // src<17b><<8 | dst_local<8b>
    }
    __syncthreads();
    for (int i = tid; i < m; i += 256) binned[beg + i] = stage[i];  // coalesced
}

// ---- build K2: per-bin total + per-bin run-placement prefix (one wave/bin) ----
__global__ __launch_bounds__(256) void k_binwave(const int* __restrict__ blkbin,
                                                 int* __restrict__ bintot,
                                                 int* __restrict__ blkpos) {
    int w = threadIdx.x >> 6, lane = threadIdx.x & 63;
    int bin = blockIdx.x * 4 + w;
    if (bin >= NBUCK) return;
    int v[PERLANE];
#pragma unroll
    for (int i = 0; i < PERLANE; ++i) v[i] = blkbin[bin * NBLK + lane * PERLANE + i];
    int mysum = 0;
#pragma unroll
    for (int i = 0; i < PERLANE; ++i) mysum += v[i];
    int pre = mysum;
#pragma unroll
    for (int o = 1; o < 64; o <<= 1) {
        int t = __shfl_up(pre, o);
        if (lane >= o) pre += t;
    }
    int excl = pre - mysum;
    int run = excl;
#pragma unroll
    for (int i = 0; i < PERLANE; ++i) {
        blkpos[bin * NBLK + lane * PERLANE + i] = run;
        run += v[i];
    }
    if (lane == 63) bintot[bin] = pre;
}

// ---- build K3: per-bucket 1024-key sort (dst_local*4 + src_quad) ----
// Emits ushort csr (src - quad*QDIV). Computes its own bucket offset.
__global__ __launch_bounds__(512) void k_sortdeg(const int* __restrict__ binned,
                                                 const int* __restrict__ blkbin,
                                                 const int* __restrict__ blkpos,
                                                 const int* __restrict__ locoff,
                                                 const int* __restrict__ bintot,
                                                 unsigned short* __restrict__ csr16,
                                                 int* __restrict__ rowseg,
                                                 float* __restrict__ dinv) {
    __shared__ int stage[SCAP];      // 32 KB
    __shared__ int runlen[NBLK];     // 2 KB
    __shared__ int runpos[NBLK];     // 2 KB
    __shared__ int cnt[1024];        // 4 KB
    __shared__ int sc[1024];         // 4 KB
    __shared__ int cur[1024];        // 4 KB
    __shared__ int bs[512];          // 2 KB
    int t = threadIdx.x;
    int b = blockIdx.x;

    // inline binscan: beg = sum(bintot[0..b)), end = beg + bintot[b]
    int part = 0;
    for (int i = t; i < b; i += 512) part += bintot[i];
    bs[t] = part;
    __syncthreads();
#pragma unroll
    for (int s = 256; s > 0; s >>= 1) {
        if (t < s) bs[t] += bs[t + s];
        __syncthreads();
    }
    int beg = bs[0];
    int end = beg + bintot[b];
    int total = end - beg;
    bool fits = (total <= SCAP);

    if (t < NBLK) {
        runlen[t] = blkbin[b * NBLK + t];
        runpos[t] = blkpos[b * NBLK + t];
    }
    cnt[t] = 0; cnt[t + 512] = 0;
    __syncthreads();

    if (fits) {
        for (int blk = t; blk < NBLK; blk += 512) {
            int len = runlen[blk];
            int srcp = locoff[blk * NBUCK + b];
            int dstp = runpos[blk];
            for (int i = 0; i < len; ++i) stage[dstp + i] = binned[srcp + i];
        }
        __syncthreads();
        for (int k = t; k < total; k += 512) {
            int p = stage[k];
            int key = ((p & 255) << 2) | ((p >> 8) / QDIV);
            atomicAdd(&cnt[key], 1);
        }
    } else {   // overflow fallback (statistically never)
        for (int blk = t; blk < NBLK; blk += 512) {
            int len = runlen[blk];
            int srcp = locoff[blk * NBUCK + b];
            for (int i = 0; i < len; ++i) {
                int p = binned[srcp + i];
                int key = ((p & 255) << 2) | ((p >> 8) / QDIV);
                atomicAdd(&cnt[key], 1);
            }
        }
    }
    __syncthreads();

    // exclusive scan over 1024 keys (2 slots/thread Hillis-Steele)
    sc[t] = cnt[t]; sc[t + 512] = cnt[t + 512];
    __syncthreads();
#pragma unroll
    for (int o = 1; o < 1024; o <<= 1) {
        int a0 = (t >= o) ? sc[t - o] : 0;
        int a1 = (t + 512 >= o) ? sc[t + 512 - o] : 0;
        __syncthreads();
        sc[t] += a0; sc[t + 512] += a1;
        __syncthreads();
    }
#pragma unroll
    for (int slot = 0; slot < 2; ++slot) {
        int k = t + slot * 512;
        int excl = sc[k] - cnt[k];
        cur[k] = excl;
        int dl = k >> 2, q = k & 3;
        int n = b * BUCKET + dl;
        if (n < N_NODES) {
            rowseg[n * 4 + q] = beg + excl;
            if (q == 0) {
                int deg = sc[k + 3] - excl;          // sum of the 4 quads
                dinv[n] = rsqrtf((float)(deg + 1));  // +1 self-loop
            }
        }
    }
    if (b == NBUCK - 1 && t == 0) rowseg[(size_t)N_NODES * 4] = end;  // sentinel
    __syncthreads();

    if (fits) {
        for (int k = t; k < total; k += 512) {
            int p = stage[k];
            int src = p >> 8;
            int q = src / QDIV;
            int key = ((p & 255) << 2) | q;
            int pos = atomicAdd(&cur[key], 1);
            csr16[beg + pos] = (unsigned short)(src - q * QDIV);
        }
    } else {
        for (int blk = t; blk < NBLK; blk += 512) {
            int len = runlen[blk];
            int srcp = locoff[blk * NBUCK + b];
            for (int i = 0; i < len; ++i) {
                int p = binned[srcp + i];
                int src = p >> 8;
                int q = src / QDIV;
                int key = ((p & 255) << 2) | q;
                int pos = atomicAdd(&cur[key], 1);
                csr16[beg + pos] = (unsigned short)(src - q * QDIV);
            }
        }
    }
}

// ================= dense helpers =================
__device__ inline void store_half8(__half* p, const float* v) {
    __half2 h[4];
#pragma unroll
    for (int i = 0; i < 4; ++i)
        h[i] = __floats2half2_rn(v[2 * i], v[2 * i + 1]);
    *(float4*)p = *(float4*)h;
}

__device__ inline void acc_half8(float* acc, float4 raw) {
    __half2* hp = (__half2*)&raw;
#pragma unroll
    for (int i = 0; i < 4; ++i) {
        float2 f = __half22float2(hp[i]);
        acc[2 * i]     += f.x;
        acc[2 * i + 1] += f.y;
    }
}

// t = relu(x@Wfc1 + bfc1); g = half( dinv * (t@Wc1) )
__global__ __launch_bounds__(256) void k_fc1_conv1(
        const float* __restrict__ x,
        const float* __restrict__ Wfc1, const float* __restrict__ bfc1,
        const float* __restrict__ Wc1, const float* __restrict__ dinv,
        __half* __restrict__ g) {
    __shared__ float  sWf[128];
    __shared__ float  sbf[32];
    __shared__ float4 sW[256];
    if (threadIdx.x < 128) sWf[threadIdx.x] = Wfc1[threadIdx.x];
    if (threadIdx.x < 32)  sbf[threadIdx.x] = bfc1[threadIdx.x];
    sW[threadIdx.x] = ((const float4*)Wc1)[threadIdx.x];
    __syncthreads();

    int n = blockIdx.x * 256 + threadIdx.x;
    if (n >= N_NODES) return;

    float4 xin = *(const float4*)(x + (size_t)n * 4);
    float t[32];
#pragma unroll
    for (int j = 0; j < 32; ++j) {
        float a = fmaf(xin.x, sWf[j], sbf[j]);
        a = fmaf(xin.y, sWf[32 + j], a);
        a = fmaf(xin.z, sWf[64 + j], a);
        a = fmaf(xin.w, sWf[96 + j], a);
        t[j] = fmaxf(a, 0.0f);
    }
    float o[32];
#pragma unroll
    for (int j = 0; j < 32; ++j) o[j] = 0.f;
#pragma unroll
    for (int k = 0; k < 32; ++k) {
        float a = t[k];
#pragma unroll
        for (int q = 0; q < 8; ++q) {
            float4 w = sW[k * 8 + q];
            o[q * 4 + 0] = fmaf(a, w.x, o[q * 4 + 0]);
            o[q * 4 + 1] = fmaf(a, w.y, o[q * 4 + 1]);
            o[q * 4 + 2] = fmaf(a, w.z, o[q * 4 + 2]);
            o[q * 4 + 3] = fmaf(a, w.w, o[q * 4 + 3]);
        }
    }
    float dv = dinv[n];
#pragma unroll
    for (int j = 0; j < 32; ++j) o[j] *= dv;
    __half* gp = g + (size_t)n * 32;
    store_half8(gp,      o);
    store_half8(gp + 8,  o + 8);
    store_half8(gp + 16, o + 16);
    store_half8(gp + 24, o + 24);
}

// ---- edge-segment accumulate over ushort csr: src = base + off ----
__device__ inline void gather_seg(int beg, int end, int base,
                                  const unsigned short* __restrict__ csr16,
                                  const __half* __restrict__ gin, int sub, float* acc) {
    int k = beg;
    int stop = beg + ((end - beg) & ~3);
    if (k < stop) {
        int s0 = base + csr16[k],     s1 = base + csr16[k + 1];
        int s2 = base + csr16[k + 2], s3 = base + csr16[k + 3];
        k += 4;
        while (k < stop) {
            float4 r0 = *(const float4*)(gin + (size_t)s0 * 32 + sub * 8);
            float4 r1 = *(const float4*)(gin + (size_t)s1 * 32 + sub * 8);
            float4 r2 = *(const float4*)(gin + (size_t)s2 * 32 + sub * 8);
            float4 r3 = *(const float4*)(gin + (size_t)s3 * 32 + sub * 8);
            s0 = base + csr16[k];     s1 = base + csr16[k + 1];
            s2 = base + csr16[k + 2]; s3 = base + csr16[k + 3];
            acc_half8(acc, r0); acc_half8(acc, r1);
            acc_half8(acc, r2); acc_half8(acc, r3);
            k += 4;
        }
        float4 r0 = *(const float4*)(gin + (size_t)s0 * 32 + sub * 8);
        float4 r1 = *(const float4*)(gin + (size_t)s1 * 32 + sub * 8);
        float4 r2 = *(const float4*)(gin + (size_t)s2 * 32 + sub * 8);
        float4 r3 = *(const float4*)(gin + (size_t)s3 * 32 + sub * 8);
        acc_half8(acc, r0); acc_half8(acc, r1);
        acc_half8(acc, r2); acc_half8(acc, r3);
    }
    for (; k < end; ++k) {
        int s = base + csr16[k];
        float4 r = *(const float4*)(gin + (size_t)s * 32 + sub * 8);
        acc_half8(acc, r);
    }
}

// ---- 4-phase soft gather + mid MLP: 4 threads/node, 64 nodes/block ----
// Per-segment calls act as wave-level phase barriers (SIMT lockstep).
__global__ __launch_bounds__(256) void k_gather_mid(
        const int* __restrict__ rowseg,
        const unsigned short* __restrict__ csr16, const __half* __restrict__ gin,
        const float* __restrict__ dinv,
        const float* __restrict__ b, const float* __restrict__ W,
        __half* __restrict__ gout) {
    __shared__ float sS[64 * 33];
    __shared__ float sW[1024];
    __shared__ float sb[32];
    for (int i = threadIdx.x; i < 1024; i += 256) sW[i] = W[i];
    if (threadIdx.x < 32) sb[threadIdx.x] = b[threadIdx.x];

    int nl = threadIdx.x >> 2;
    int sub = threadIdx.x & 3;
    int n = blockIdx.x * 64 + nl;
    float acc[8];
    if (n < N_NODES) {
        float4 self = *(const float4*)(gin + (size_t)n * 32 + sub * 8);
        {
            __half2* hp = (__half2*)&self;
#pragma unroll
            for (int i = 0; i < 4; ++i) {
                float2 f = __half22float2(hp[i]);
                acc[2 * i] = f.x;
                acc[2 * i + 1] = f.y;
            }
        }
        int4 seg = *(const int4*)(rowseg + (size_t)n * 4);
        int segend = rowseg[(size_t)n * 4 + 4];          // next start / sentinel
        gather_seg(seg.x, seg.y, 0,         csr16, gin, sub, acc);   // quad 0
        gather_seg(seg.y, seg.z, QDIV,      csr16, gin, sub, acc);   // quad 1
        gather_seg(seg.z, seg.w, 2 * QDIV,  csr16, gin, sub, acc);   // quad 2
        gather_seg(seg.w, segend, 3 * QDIV, csr16, gin, sub, acc);   // quad 3
#pragma unroll
        for (int i = 0; i < 8; ++i) sS[nl * 33 + sub * 8 + i] = acc[i];
    }
    __syncthreads();

    if (n >= N_NODES) return;
    float dv = dinv[n];
    float t[32];
#pragma unroll
    for (int kk = 0; kk < 32; ++kk)
        t[kk] = fmaxf(fmaf(dv, sS[nl * 33 + kk], sb[kk]), 0.0f);
    float o[8];
#pragma unroll
    for (int j = 0; j < 8; ++j) o[j] = 0.f;
#pragma unroll
    for (int kk = 0; kk < 32; ++kk) {
        float a = t[kk];
#pragma unroll
        for (int j = 0; j < 8; ++j)
            o[j] = fmaf(a, sW[kk * 32 + sub * 8 + j], o[j]);
    }
#pragma unroll
    for (int j = 0; j < 8; ++j) o[j] *= dv;
    store_half8(gout + (size_t)n * 32 + sub * 8, o);
}

// ---- 4-phase soft gather + final layer ----
__global__ __launch_bounds__(256) void k_gather_out(
        const int* __restrict__ rowseg,
        const unsigned short* __restrict__ csr16, const __half* __restrict__ gin,
        const float* __restrict__ dinv,
        const float* __restrict__ bc3, const float* __restrict__ Wfc2,
        const float* __restrict__ bfc2, float* __restrict__ out) {
    __shared__ float sS[64 * 33];
    __shared__ float sW[96];
    __shared__ float sb[32];
    __shared__ float sb2[3];
    if (threadIdx.x < 96) sW[threadIdx.x] = Wfc2[threadIdx.x];
    if (threadIdx.x < 32) sb[threadIdx.x] = bc3[threadIdx.x];
    if (threadIdx.x < 3)  sb2[threadIdx.x] = bfc2[threadIdx.x];

    int nl = threadIdx.x >> 2;
    int sub = threadIdx.x & 3;
    int n = blockIdx.x * 64 + nl;
    float acc[8];
    if (n < N_NODES) {
        float4 self = *(const float4*)(gin + (size_t)n * 32 + sub * 8);
        {
            __half2* hp = (__half2*)&self;
#pragma unroll
            for (int i = 0; i < 4; ++i) {
                float2 f = __half22float2(hp[i]);
                acc[2 * i] = f.x;
                acc[2 * i + 1] = f.y;
            }
        }
        int4 seg = *(const int4*)(rowseg + (size_t)n * 4);
        int segend = rowseg[(size_t)n * 4 + 4];
        gather_seg(seg.x, seg.y, 0,         csr16, gin, sub, acc);
        gather_seg(seg.y, seg.z, QDIV,      csr16, gin, sub, acc);
        gather_seg(seg.z, seg.w, 2 * QDIV,  csr16, gin, sub, acc);
        gather_seg(seg.w, segend, 3 * QDIV, csr16, gin, sub, acc);
#pragma unroll
        for (int i = 0; i < 8; ++i) sS[nl * 33 + sub * 8 + i] = acc[i];
    }
    __syncthreads();

    if (n >= N_NODES || sub != 0) return;
    float dv = dinv[n];
    float t[32];
#pragma unroll
    for (int kk = 0; kk < 32; ++kk)
        t[kk] = fmaxf(fmaf(dv, sS[nl * 33 + kk], sb[kk]), 0.0f);
    float o0 = sb2[0], o1 = sb2[1], o2 = sb2[2];
#pragma unroll
    for (int kk = 0; kk < 32; ++kk) {
        o0 = fmaf(t[kk], sW[kk * 3 + 0], o0);
        o1 = fmaf(t[kk], sW[kk * 3 + 1], o1);
        o2 = fmaf(t[kk], sW[kk * 3 + 2], o2);
    }
    out[(size_t)n * 3 + 0] = o0;
    out[(size_t)n * 3 + 1] = o1;
    out[(size_t)n * 3 + 2] = o2;
}

extern "C" void kernel_launch(void* const* d_in, const int* in_sizes, int n_in,
                              void* d_out, int out_size, void* d_ws, size_t ws_size,
                              hipStream_t stream) {
    const float* x    = (const float*)d_in[0];
    const int*   ei   = (const int*)d_in[1];
    const float* Wfc1 = (const float*)d_in[2];
    const float* bfc1 = (const float*)d_in[3];
    const float* Wc1  = (const float*)d_in[4];
    const float* bc1  = (const float*)d_in[5];
    const float* Wc2  = (const float*)d_in[6];
    const float* bc2  = (const float*)d_in[7];
    const float* Wc3  = (const float*)d_in[8];
    const float* bc3  = (const float*)d_in[9];
    const float* Wfc2 = (const float*)d_in[10];
    const float* bfc2 = (const float*)d_in[11];
    float* out = (float*)d_out;

    char* ws = (char*)d_ws;
    const size_t grow = (size_t)N_NODES * 32 * sizeof(__half);   // 6.4 MB
    size_t off = 0;
    __half* gA     = (__half*)(ws + off); off += grow;
    __half* gB     = (__half*)(ws + off); off += grow;
    int*   binned  = (int*)  (ws + off); off += (size_t)NBLK * CHUNK * sizeof(int);
    unsigned short* csr16 = (unsigned short*)(ws + off);
    off += ((size_t)N_EDGES + 8) * sizeof(unsigned short);
    float* dinv    = (float*)(ws + off); off += (size_t)N_NODES * sizeof(float);
    int*   rowseg  = (int*)  (ws + off); off += ((size_t)N_NODES * 4 + 16) * sizeof(int);
    int*   blkbin  = (int*)  (ws + off); off += (size_t)NBUCK * NBLK * sizeof(int);
    int*   blkpos  = (int*)  (ws + off); off += (size_t)NBUCK * NBLK * sizeof(int);
    int*   locoff  = (int*)  (ws + off); off += (size_t)NBLK * NBUCK * sizeof(int);
    int*   bintot  = (int*)  (ws + off); off += (size_t)NBUCK * sizeof(int);

    const int nb_wave = (NBUCK + 3) / 4;              // 98
    const int nb_n = (N_NODES + 255) / 256;           // 391
    const int nb_f = (N_NODES * 4 + 255) / 256;       // 1563 (4 thr/node)

    k_binfill<<<NBLK, 256, 0, stream>>>(ei, binned, blkbin, locoff);
    k_binwave<<<nb_wave, 256, 0, stream>>>(blkbin, bintot, blkpos);
    k_sortdeg<<<NBUCK, 512, 0, stream>>>(binned, blkbin, blkpos, locoff, bintot,
                                         csr16, rowseg, dinv);

    k_fc1_conv1<<<nb_n, 256, 0, stream>>>(x, Wfc1, bfc1, Wc1, dinv, gA);
    k_gather_mid<<<nb_f, 256, 0, stream>>>(rowseg, csr16, gA, dinv, bc1, Wc2, gB);
    k_gather_mid<<<nb_f, 256, 0, stream>>>(rowseg, csr16, gB, dinv, bc2, Wc3, gA);
    k_gather_out<<<nb_f, 256, 0, stream>>>(rowseg, csr16, gA, dinv, bc3, Wfc2, bfc2, out);
}